// Round 9
// baseline (543.943 us; speedup 1.0000x reference)
//
#include <hip/hip_runtime.h>

// GCN1 on MI355X. Rounds 4-8 established: random 4-8B gathers run at a fixed
// ~7 cyc/edge/CU, invariant to occupancy, ILP depth, and src locality ->
// per-CU outstanding-miss cap (every gather is a cold L1 line: 16 uses/node
// spread over 245 buckets = no reuse). Round-9: eliminate gathers. classort
// (proven r7) now uses 2048-node slices (245 classes == src>>11) and emits
// per-(bucket,slice) offsets; consumers process 2-bucket groups with LDS acc
// (16/32KB) looping slices: stage slice xs/yd (8/16KB, L2-resident) into LDS,
// then edges consume via ds_read + LDS atomic. Zero VMEM gathers.
//
// Algebra (validated r1-r8, absmax 3.9e-3): layer1 collapses to a scalar
// aggregate (x is [N,1]); layer2 aggregates only the 2-wide y = h1@W2.

static constexpr int BKT_BITS = 11;
static constexpr int BKT = 1 << BKT_BITS;  // 2048 nodes/bucket == slice size
static constexpr int NB = 256;             // padded bucket count (nbkt=245)
static constexpr int HB = 512;             // hist blocks
static constexpr int HT = 256;
static constexpr int CHUNK = 8192;         // edges per scatter block
static constexpr int SCT = 256;
static constexpr int PERT = CHUNK / SCT;   // 32 edges/thread
static constexpr int NCLS = 245;           // slice classes (src>>11)
static constexpr int NCLSP = 248;          // pad: NCLSP*NW = 3968 (mult of 64)
static constexpr int NW = 16;              // waves per classort block

using u32x4 = __attribute__((ext_vector_type(4))) unsigned;

// ---- 1. per-bucket totals ----
__global__ void __launch_bounds__(HT) k_hist(const int* __restrict__ dst, int e,
                                             int chunk, int nbkt,
                                             unsigned* __restrict__ totals) {
  __shared__ unsigned cnt[NB];
  for (int t = threadIdx.x; t < NB; t += HT) cnt[t] = 0;
  __syncthreads();
  int lo = blockIdx.x * chunk;  // chunk multiple of 4
  int hi = min(lo + chunk, e);
  const int4* d4 = (const int4*)dst;
  for (int i = (lo >> 2) + threadIdx.x; i < (hi >> 2); i += HT) {
    int4 d = d4[i];
    atomicAdd(&cnt[((unsigned)d.x) >> BKT_BITS], 1u);
    atomicAdd(&cnt[((unsigned)d.y) >> BKT_BITS], 1u);
    atomicAdd(&cnt[((unsigned)d.z) >> BKT_BITS], 1u);
    atomicAdd(&cnt[((unsigned)d.w) >> BKT_BITS], 1u);
  }
  for (int i = ((hi >> 2) << 2) + threadIdx.x; i < hi; i += HT)
    atomicAdd(&cnt[((unsigned)dst[i]) >> BKT_BITS], 1u);
  __syncthreads();
  for (int t = threadIdx.x; t < nbkt; t += HT)
    if (cnt[t]) atomicAdd(&totals[t], cnt[t]);
}

// ---- 2. exclusive scan of totals -> gcur ----
__global__ void k_basescan(const unsigned* __restrict__ totals, int nbkt,
                           unsigned* __restrict__ gcur) {
  int lane = threadIdx.x;  // 64
  unsigned running = 0;
  for (int c = 0; c < NB; c += 64) {
    int k = c + lane;
    unsigned v = (k < nbkt) ? totals[k] : 0u;
    unsigned incl = v;
#pragma unroll
    for (int off = 1; off < 64; off <<= 1) {
      unsigned t = __shfl_up(incl, off);
      if (lane >= off) incl += t;
    }
    if (k < nbkt) gcur[k] = running + incl - v;
    running += __shfl(incl, 63);
  }
}

// ---- 3. scatter: block-local 245-bucket sort + linear copy-out (proven) ----
__global__ void __launch_bounds__(SCT) k_scatter(
    const int* __restrict__ src, const int* __restrict__ dst, int e, int nbkt,
    unsigned* __restrict__ gcur, unsigned* __restrict__ packed) {
  __shared__ unsigned staged[CHUNK];  // 32 KB
  __shared__ unsigned cnt[NB];
  __shared__ unsigned cur[NB];
  __shared__ unsigned gseg[NB];
  __shared__ unsigned loff[NB + 1];
  const int tid = threadIdx.x;
  const int lo = blockIdx.x * CHUNK;
  for (int t = tid; t < NB; t += SCT) { cnt[t] = 0u; cur[t] = 0u; }
  __syncthreads();

  unsigned pk[PERT];
  unsigned bku[PERT / 4];
  const int4* s4 = (const int4*)src;
  const int4* d4 = (const int4*)dst;
#pragma unroll
  for (int jj = 0; jj < PERT / 4; ++jj) {
    int i4 = (lo >> 2) + jj * SCT + tid;
    unsigned b4 = 0xFFFFFFFFu;
    if (i4 * 4 + 3 < e) {
      int4 s = s4[i4];
      int4 d = d4[i4];
      unsigned k0 = ((unsigned)d.x) >> BKT_BITS, k1 = ((unsigned)d.y) >> BKT_BITS;
      unsigned k2 = ((unsigned)d.z) >> BKT_BITS, k3 = ((unsigned)d.w) >> BKT_BITS;
      pk[jj * 4 + 0] = ((unsigned)s.x << BKT_BITS) | ((unsigned)d.x & (BKT - 1));
      pk[jj * 4 + 1] = ((unsigned)s.y << BKT_BITS) | ((unsigned)d.y & (BKT - 1));
      pk[jj * 4 + 2] = ((unsigned)s.z << BKT_BITS) | ((unsigned)d.z & (BKT - 1));
      pk[jj * 4 + 3] = ((unsigned)s.w << BKT_BITS) | ((unsigned)d.w & (BKT - 1));
      b4 = k0 | (k1 << 8) | (k2 << 16) | (k3 << 24);
      atomicAdd(&cnt[k0], 1u);
      atomicAdd(&cnt[k1], 1u);
      atomicAdd(&cnt[k2], 1u);
      atomicAdd(&cnt[k3], 1u);
    } else {
#pragma unroll
      for (int c = 0; c < 4; ++c) {
        int i = i4 * 4 + c;
        if (i >= lo && i < e) {
          unsigned dd = (unsigned)dst[i];
          unsigned kk = dd >> BKT_BITS;
          pk[jj * 4 + c] = ((unsigned)src[i] << BKT_BITS) | (dd & (BKT - 1));
          b4 = (b4 & ~(0xFFu << (8 * c))) | (kk << (8 * c));
          atomicAdd(&cnt[kk], 1u);
        }
      }
    }
    bku[jj] = b4;
  }
  __syncthreads();

  if (tid < 64) {
    unsigned running = 0;
    for (int c = 0; c < NB; c += 64) {
      int k = c + tid;
      unsigned v = cnt[k];
      unsigned incl = v;
#pragma unroll
      for (int off = 1; off < 64; off <<= 1) {
        unsigned t = __shfl_up(incl, off);
        if (tid >= off) incl += t;
      }
      loff[k] = running + incl - v;
      running += __shfl(incl, 63);
    }
    if (tid == 0) loff[NB] = running;
  }
  __syncthreads();

  for (int k = tid; k < nbkt; k += SCT)
    if (cnt[k]) gseg[k] = atomicAdd(&gcur[k], cnt[k]);

#pragma unroll
  for (int jj = 0; jj < PERT / 4; ++jj) {
    unsigned b4 = bku[jj];
#pragma unroll
    for (int c = 0; c < 4; ++c) {
      unsigned k = (b4 >> (8 * c)) & 0xFFu;
      if (k != 0xFFu) {
        unsigned pos = loff[k] + atomicAdd(&cur[k], 1u);
        staged[pos] = pk[jj * 4 + c];
      }
    }
  }
  __syncthreads();

  int mv = (int)loff[NB];
  for (int t = tid; t < mv; t += SCT) {
    int a = 0, b = nbkt;
    while (b - a > 1) {
      int mid = (a + b) >> 1;
      if ((int)loff[mid] <= t) a = mid; else b = mid;
    }
    __builtin_nontemporal_store(staged[t],
                                packed + gseg[a] + (unsigned)(t - (int)loff[a]));
  }
}

// ---- 4. per-bucket slice sort (245 classes) + sliceoff + deg16 + xs ----
__global__ void __launch_bounds__(1024) k_classort(
    const unsigned* __restrict__ packed, const unsigned* __restrict__ gcur,
    const float* __restrict__ x, int n, unsigned* __restrict__ packed2,
    unsigned* __restrict__ sliceoff, unsigned short* __restrict__ deg16,
    float* __restrict__ xs) {
  __shared__ unsigned cnt_node[BKT];       // 8 KB
  __shared__ unsigned wcnt[NCLSP * NW];    // 15.5 KB
  __shared__ unsigned wcur[NCLSP * NW];    // 15.5 KB
  const int k = blockIdx.x;
  const int tid = threadIdx.x;
  const int w = tid >> 6;
  for (int t = tid; t < BKT; t += 1024) cnt_node[t] = 0;
  for (int t = tid; t < NCLSP * NW; t += 1024) wcnt[t] = 0;
  __syncthreads();
  unsigned lo = k ? gcur[k - 1] : 0u, hi = gcur[k];
  unsigned loA = (lo + 3u) & ~3u, hiA = hi & ~3u;
  if (loA > hi) loA = hi;
  if (hiA < loA) hiA = loA;

  // phase 1: node degree + per-(class,wave) counts
  for (unsigned i = lo + tid; i < loA; i += 1024) {
    unsigned p = packed[i];
    atomicAdd(&cnt_node[p & (BKT - 1)], 1u);
    atomicAdd(&wcnt[(p >> 22) * NW + w], 1u);
  }
  for (unsigned i = hiA + tid; i < hi; i += 1024) {
    unsigned p = packed[i];
    atomicAdd(&cnt_node[p & (BKT - 1)], 1u);
    atomicAdd(&wcnt[(p >> 22) * NW + w], 1u);
  }
  const u32x4* p4 = (const u32x4*)packed;
  for (unsigned q = (loA >> 2) + tid; q < (hiA >> 2); q += 1024) {
    u32x4 p = p4[q];
    atomicAdd(&cnt_node[p.x & (BKT - 1)], 1u);
    atomicAdd(&wcnt[(p.x >> 22) * NW + w], 1u);
    atomicAdd(&cnt_node[p.y & (BKT - 1)], 1u);
    atomicAdd(&wcnt[(p.y >> 22) * NW + w], 1u);
    atomicAdd(&cnt_node[p.z & (BKT - 1)], 1u);
    atomicAdd(&wcnt[(p.z >> 22) * NW + w], 1u);
    atomicAdd(&cnt_node[p.w & (BKT - 1)], 1u);
    atomicAdd(&wcnt[(p.w >> 22) * NW + w], 1u);
  }
  __syncthreads();

  // wave-0 scan of 3968 (class-major, wave-minor); emit per-class starts
  if (tid < 64) {
    unsigned running = 0;
    for (int c = 0; c < NCLSP * NW; c += 64) {
      int idx = c + tid;
      unsigned v = wcnt[idx];
      unsigned incl = v;
#pragma unroll
      for (int off = 1; off < 64; off <<= 1) {
        unsigned t = __shfl_up(incl, off);
        if (tid >= off) incl += t;
      }
      unsigned excl = running + incl - v;
      wcur[idx] = excl;
      if ((idx & (NW - 1)) == 0 && (idx >> 4) <= NCLS)
        sliceoff[k * (NCLS + 1) + (idx >> 4)] = excl;
      running += __shfl(incl, 63);
    }
  }
  __syncthreads();

  // phase 2: place into slice-grouped order
  for (unsigned i = lo + tid; i < loA; i += 1024) {
    unsigned p = packed[i];
    packed2[lo + atomicAdd(&wcur[(p >> 22) * NW + w], 1u)] = p;
  }
  for (unsigned i = hiA + tid; i < hi; i += 1024) {
    unsigned p = packed[i];
    packed2[lo + atomicAdd(&wcur[(p >> 22) * NW + w], 1u)] = p;
  }
  for (unsigned q = (loA >> 2) + tid; q < (hiA >> 2); q += 1024) {
    u32x4 p = p4[q];
    packed2[lo + atomicAdd(&wcur[(p.x >> 22) * NW + w], 1u)] = p.x;
    packed2[lo + atomicAdd(&wcur[(p.y >> 22) * NW + w], 1u)] = p.y;
    packed2[lo + atomicAdd(&wcur[(p.z >> 22) * NW + w], 1u)] = p.z;
    packed2[lo + atomicAdd(&wcur[(p.w >> 22) * NW + w], 1u)] = p.w;
  }

  // epilogue: deg16 + xs
  int g0 = k << BKT_BITS;
  for (int t = tid; t < BKT; t += 1024) {
    int g = g0 + t;
    if (g < n) {
      unsigned d = cnt_node[t];
      deg16[g] = (unsigned short)(d > 65535u ? 65535u : d);
      xs[g] = rsqrtf((float)(d + 1u)) * x[g];
    }
  }
}

// ---- 5. layer-1 tiled aggregate: 2-bucket groups, LDS-staged slices ----
__global__ void __launch_bounds__(1024) k_accA_tile(
    const unsigned* __restrict__ packed2, const unsigned* __restrict__ gcur,
    const unsigned* __restrict__ sliceoff, const float* __restrict__ xs,
    int nbkt, float* __restrict__ pA) {
  __shared__ float acc[2 * BKT];  // 16 KB (4096 dsts)
  __shared__ float stg[BKT];      // 8 KB (slice of xs)
  const int g = blockIdx.x >> 1, p = blockIdx.x & 1;
  for (int t = threadIdx.x; t < 2 * BKT; t += 1024) acc[t] = 0.0f;
  const int w = threadIdx.x >> 6, lane = threadIdx.x & 63;
  const int bkL = w & 1, sub = w >> 1;  // 8 sub-waves per bucket
  const int bk = g * 2 + bkL;
  unsigned bs = 0, soBase = 0;
  if (bk < nbkt) {
    bs = bk ? gcur[bk - 1] : 0u;
    soBase = (unsigned)bk * (NCLS + 1);
  }
  __syncthreads();
  for (int s = p; s < NCLS; s += 2) {
    for (int j = threadIdx.x; j < BKT; j += 1024)
      stg[j] = xs[(s << BKT_BITS) + j];  // tail slice over-reads ws (unused)
    __syncthreads();
    if (bk < nbkt) {
      unsigned slo = bs + sliceoff[soBase + s];
      unsigned shi = bs + sliceoff[soBase + s + 1];
      for (unsigned i = slo + (unsigned)(sub * 64 + lane); i < shi; i += 512u) {
        unsigned ww = packed2[i];
        atomicAdd(&acc[(bkL << BKT_BITS) | (ww & (BKT - 1))],
                  stg[(ww >> BKT_BITS) & (BKT - 1)]);
      }
    }
    __syncthreads();
  }
  float* dstp = pA + ((size_t)blockIdx.x << 12);
  for (int t = threadIdx.x; t < 2 * BKT; t += 1024)
    __builtin_nontemporal_store(acc[t], dstp + t);
}

// ---- 6. node epilogue A: merge 2 partials + MLP 1->32->2 -> yd ----
__global__ void __launch_bounds__(256) k_nodeA(
    const float* __restrict__ pA, const unsigned short* __restrict__ deg16,
    const float* __restrict__ xs, const float* __restrict__ W1,
    const float* __restrict__ b1, const float* __restrict__ W2, int n,
    float2* __restrict__ yd) {
  __shared__ float sW1[32], sb1[32], sW2[64];
  if (threadIdx.x < 32) {
    sW1[threadIdx.x] = W1[threadIdx.x];
    sb1[threadIdx.x] = b1[threadIdx.x];
  } else if (threadIdx.x < 96) {
    sW2[threadIdx.x - 32] = W2[threadIdx.x - 32];
  }
  __syncthreads();
  int g = blockIdx.x * 256 + threadIdx.x;
  if (g >= n) return;
  int gr = g >> 12, local = g & 4095;
  float a = pA[((size_t)(gr * 2) << 12) + local] +
            pA[((size_t)(gr * 2 + 1) << 12) + local];
  float di = rsqrtf((float)(deg16[g] + 1u));
  float sv = di * (a + xs[g]);  // self-loop: dinv^2*x = dinv*xs
  float y0 = 0.0f, y1 = 0.0f;
#pragma unroll
  for (int f = 0; f < 32; ++f) {
    float h = fmaxf(fmaf(sv, sW1[f], sb1[f]), 0.0f);
    y0 = fmaf(h, sW2[2 * f + 0], y0);
    y1 = fmaf(h, sW2[2 * f + 1], y1);
  }
  yd[g] = make_float2(di * y0, di * y1);
}

// ---- 7. layer-2 tiled aggregate (float2) ----
__global__ void __launch_bounds__(1024) k_accB_tile(
    const unsigned* __restrict__ packed2, const unsigned* __restrict__ gcur,
    const unsigned* __restrict__ sliceoff, const float2* __restrict__ yd,
    int nbkt, float2* __restrict__ pB) {
  __shared__ float a0[2 * BKT], a1[2 * BKT];  // 32 KB
  __shared__ float2 stg[BKT];                 // 16 KB
  const int g = blockIdx.x >> 1, p = blockIdx.x & 1;
  for (int t = threadIdx.x; t < 2 * BKT; t += 1024) {
    a0[t] = 0.0f;
    a1[t] = 0.0f;
  }
  const int w = threadIdx.x >> 6, lane = threadIdx.x & 63;
  const int bkL = w & 1, sub = w >> 1;
  const int bk = g * 2 + bkL;
  unsigned bs = 0, soBase = 0;
  if (bk < nbkt) {
    bs = bk ? gcur[bk - 1] : 0u;
    soBase = (unsigned)bk * (NCLS + 1);
  }
  __syncthreads();
  for (int s = p; s < NCLS; s += 2) {
    for (int j = threadIdx.x; j < BKT; j += 1024)
      stg[j] = yd[(s << BKT_BITS) + j];
    __syncthreads();
    if (bk < nbkt) {
      unsigned slo = bs + sliceoff[soBase + s];
      unsigned shi = bs + sliceoff[soBase + s + 1];
      for (unsigned i = slo + (unsigned)(sub * 64 + lane); i < shi; i += 512u) {
        unsigned ww = packed2[i];
        unsigned d = (bkL << BKT_BITS) | (ww & (BKT - 1));
        float2 v = stg[(ww >> BKT_BITS) & (BKT - 1)];
        atomicAdd(&a0[d], v.x);
        atomicAdd(&a1[d], v.y);
      }
    }
    __syncthreads();
  }
  float2* dstp = pB + ((size_t)blockIdx.x << 12);
  for (int t = threadIdx.x; t < 2 * BKT; t += 1024)
    dstp[t] = make_float2(a0[t], a1[t]);
}

// ---- 8. node epilogue B: merge 2 partials + log-softmax ----
__global__ void __launch_bounds__(256) k_nodeB(
    const float2* __restrict__ pB, const unsigned short* __restrict__ deg16,
    const float2* __restrict__ yd, const float* __restrict__ b2, int n,
    float2* __restrict__ out) {
  int g = blockIdx.x * 256 + threadIdx.x;
  if (g >= n) return;
  int gr = g >> 12, local = g & 4095;
  float2 v0 = pB[((size_t)(gr * 2) << 12) + local];
  float2 v1 = pB[((size_t)(gr * 2 + 1) << 12) + local];
  float di = rsqrtf((float)(deg16[g] + 1u));
  float2 yv = yd[g];
  float t0 = fmaf(di, v0.x + v1.x + yv.x, b2[0]);
  float t1 = fmaf(di, v0.y + v1.y + yv.y, b2[1]);
  float m = fmaxf(t0, t1);
  float l = m + logf(expf(t0 - m) + expf(t1 - m));
  out[g] = make_float2(t0 - l, t1 - l);
}

extern "C" void kernel_launch(void* const* d_in, const int* in_sizes, int n_in,
                              void* d_out, int out_size, void* d_ws, size_t ws_size,
                              hipStream_t stream) {
  const float* x = (const float*)d_in[0];
  const int* edge = (const int*)d_in[1];  // int64 inputs arrive as int32
  const float* W1 = (const float*)d_in[2];
  const float* b1 = (const float*)d_in[3];
  const float* W2 = (const float*)d_in[4];
  const float* b2 = (const float*)d_in[5];
  float2* out = (float2*)d_out;

  const int n = in_sizes[0];      // 500000
  const int e = in_sizes[1] / 2;  // 8000000
  const int* src = edge;
  const int* dst = edge + e;

  const int nbkt = (n + BKT - 1) >> BKT_BITS;         // 245
  const int hchunk = (((e + HB - 1) / HB) + 3) & ~3;  // mult of 4
  const int sgrid = (e + CHUNK - 1) / CHUNK;          // 977
  const int ngrid = (n + 255) / 256;                  // 1954
  const int ngrp2 = (nbkt + 1) / 2;                   // 123 two-bucket groups

  // ---- workspace (~71.3 MB; <= 72.05 MB proven available in round 4) ----
  char* ws = (char*)d_ws;
  size_t off = 0;
  unsigned* packed = (unsigned*)(ws + off);   off += (size_t)e * 4;  // 32 MB
  unsigned* packed2 = (unsigned*)(ws + off);  off += (size_t)e * 4;  // 32 MB
  unsigned* totals = (unsigned*)(ws + off);   off += NB * 4;
  unsigned* gcur = (unsigned*)(ws + off);     off += NB * 4;
  unsigned* sliceoff = (unsigned*)(ws + off); off += (size_t)nbkt * (NCLS + 1) * 4;  // 241 KB
  unsigned short* deg16 = (unsigned short*)(ws + off); off += (size_t)n * 2;  // 1 MB
  float* xs = (float*)(ws + off);             off += (size_t)n * 4;  // 2 MB
  float2* yd = (float2*)(ws + off);           off += (size_t)n * 8;  // 4 MB
  // partials overlay the (dead after classort) packed region:
  float* pA = (float*)packed;                  // 246*4096*4 = 4 MB
  float2* pB = (float2*)(ws + (size_t)8 * 1024 * 1024);  // 8 MB, still in packed

  hipMemsetAsync(totals, 0, NB * sizeof(unsigned), stream);
  k_hist<<<HB, HT, 0, stream>>>(dst, e, hchunk, nbkt, totals);
  k_basescan<<<1, 64, 0, stream>>>(totals, nbkt, gcur);
  k_scatter<<<sgrid, SCT, 0, stream>>>(src, dst, e, nbkt, gcur, packed);
  // after k_scatter: gcur[k] == end of bucket k
  k_classort<<<nbkt, 1024, 0, stream>>>(packed, gcur, x, n, packed2, sliceoff,
                                        deg16, xs);
  k_accA_tile<<<ngrp2 * 2, 1024, 0, stream>>>(packed2, gcur, sliceoff, xs, nbkt,
                                              pA);
  k_nodeA<<<ngrid, 256, 0, stream>>>(pA, deg16, xs, W1, b1, W2, n, yd);
  k_accB_tile<<<ngrp2 * 2, 1024, 0, stream>>>(packed2, gcur, sliceoff, yd, nbkt,
                                              pB);
  k_nodeB<<<ngrid, 256, 0, stream>>>(pB, deg16, yd, b2, n, out);
}

// Round 10
// 367.308 us; speedup vs baseline: 1.4809x; 1.4809x over previous
//
#include <hip/hip_runtime.h>

// GCN1 on MI355X. The ~92us/pass random-gather wall = 8M cold 64B L2 lines
// (512MB at ~5.6TB/s random-line ceiling), invariant to occupancy/ILP/order.
// Round-9's 2-bucket tiles had staging ratio 7.7x + 122 barrier iters -> 211us.
// Round-10: same idea, correct geometry. Pass A: 12-bucket groups (96KB acc)
// x 12 slice-ranges = 252 blocks, 21 iters, ~1600 edges/iter, staging ratio
// ~1.0. Pass B: 6-bucket groups x 6 ranges = 246 blocks, 41 iters, ~800
// edges/iter. Double-buffered slice staging (issue loads early, write after
// barrier = T14) hides HBM/L2 latency under LDS-atomic edge work.
//
// Algebra (validated r1-r9, absmax 3.9e-3): layer1 collapses to a scalar
// aggregate (x is [N,1]); layer2 aggregates only the 2-wide y = h1@W2.

static constexpr int BKT_BITS = 11;
static constexpr int BKT = 1 << BKT_BITS;  // 2048 nodes/bucket == slice size
static constexpr int NB = 256;             // padded bucket count (nbkt=245)
static constexpr int HB = 512;             // hist blocks
static constexpr int HT = 256;
static constexpr int CHUNK = 8192;         // edges per scatter block
static constexpr int SCT = 256;
static constexpr int PERT = CHUNK / SCT;   // 32 edges/thread
static constexpr int NCLS = 245;           // slice classes (src>>11)
static constexpr int NCLSP = 248;          // pad: NCLSP*NW = 3968 (mult of 64)
static constexpr int NW = 16;              // waves per 1024-thr block
static constexpr int GA = 12;              // buckets/group, pass A (96KB acc)
static constexpr int RA = 12;              // slice-ranges, pass A
static constexpr int NSA = (NCLS + RA - 1) / RA;  // 21 slices/range
static constexpr int GB = 6;               // buckets/group, pass B (96KB acc)
static constexpr int RB = 6;               // slice-ranges, pass B
static constexpr int NSB = (NCLS + RB - 1) / RB;  // 41 slices/range

using u32x4 = __attribute__((ext_vector_type(4))) unsigned;

// ---- 1. per-bucket totals ----
__global__ void __launch_bounds__(HT) k_hist(const int* __restrict__ dst, int e,
                                             int chunk, int nbkt,
                                             unsigned* __restrict__ totals) {
  __shared__ unsigned cnt[NB];
  for (int t = threadIdx.x; t < NB; t += HT) cnt[t] = 0;
  __syncthreads();
  int lo = blockIdx.x * chunk;  // chunk multiple of 4
  int hi = min(lo + chunk, e);
  const int4* d4 = (const int4*)dst;
  for (int i = (lo >> 2) + threadIdx.x; i < (hi >> 2); i += HT) {
    int4 d = d4[i];
    atomicAdd(&cnt[((unsigned)d.x) >> BKT_BITS], 1u);
    atomicAdd(&cnt[((unsigned)d.y) >> BKT_BITS], 1u);
    atomicAdd(&cnt[((unsigned)d.z) >> BKT_BITS], 1u);
    atomicAdd(&cnt[((unsigned)d.w) >> BKT_BITS], 1u);
  }
  for (int i = ((hi >> 2) << 2) + threadIdx.x; i < hi; i += HT)
    atomicAdd(&cnt[((unsigned)dst[i]) >> BKT_BITS], 1u);
  __syncthreads();
  for (int t = threadIdx.x; t < nbkt; t += HT)
    if (cnt[t]) atomicAdd(&totals[t], cnt[t]);
}

// ---- 2. exclusive scan of totals -> gcur ----
__global__ void k_basescan(const unsigned* __restrict__ totals, int nbkt,
                           unsigned* __restrict__ gcur) {
  int lane = threadIdx.x;  // 64
  unsigned running = 0;
  for (int c = 0; c < NB; c += 64) {
    int k = c + lane;
    unsigned v = (k < nbkt) ? totals[k] : 0u;
    unsigned incl = v;
#pragma unroll
    for (int off = 1; off < 64; off <<= 1) {
      unsigned t = __shfl_up(incl, off);
      if (lane >= off) incl += t;
    }
    if (k < nbkt) gcur[k] = running + incl - v;
    running += __shfl(incl, 63);
  }
}

// ---- 3. scatter: block-local 245-bucket sort + linear copy-out (proven) ----
__global__ void __launch_bounds__(SCT) k_scatter(
    const int* __restrict__ src, const int* __restrict__ dst, int e, int nbkt,
    unsigned* __restrict__ gcur, unsigned* __restrict__ packed) {
  __shared__ unsigned staged[CHUNK];  // 32 KB
  __shared__ unsigned cnt[NB];
  __shared__ unsigned cur[NB];
  __shared__ unsigned gseg[NB];
  __shared__ unsigned loff[NB + 1];
  const int tid = threadIdx.x;
  const int lo = blockIdx.x * CHUNK;
  for (int t = tid; t < NB; t += SCT) { cnt[t] = 0u; cur[t] = 0u; }
  __syncthreads();

  unsigned pk[PERT];
  unsigned bku[PERT / 4];
  const int4* s4 = (const int4*)src;
  const int4* d4 = (const int4*)dst;
#pragma unroll
  for (int jj = 0; jj < PERT / 4; ++jj) {
    int i4 = (lo >> 2) + jj * SCT + tid;
    unsigned b4 = 0xFFFFFFFFu;
    if (i4 * 4 + 3 < e) {
      int4 s = s4[i4];
      int4 d = d4[i4];
      unsigned k0 = ((unsigned)d.x) >> BKT_BITS, k1 = ((unsigned)d.y) >> BKT_BITS;
      unsigned k2 = ((unsigned)d.z) >> BKT_BITS, k3 = ((unsigned)d.w) >> BKT_BITS;
      pk[jj * 4 + 0] = ((unsigned)s.x << BKT_BITS) | ((unsigned)d.x & (BKT - 1));
      pk[jj * 4 + 1] = ((unsigned)s.y << BKT_BITS) | ((unsigned)d.y & (BKT - 1));
      pk[jj * 4 + 2] = ((unsigned)s.z << BKT_BITS) | ((unsigned)d.z & (BKT - 1));
      pk[jj * 4 + 3] = ((unsigned)s.w << BKT_BITS) | ((unsigned)d.w & (BKT - 1));
      b4 = k0 | (k1 << 8) | (k2 << 16) | (k3 << 24);
      atomicAdd(&cnt[k0], 1u);
      atomicAdd(&cnt[k1], 1u);
      atomicAdd(&cnt[k2], 1u);
      atomicAdd(&cnt[k3], 1u);
    } else {
#pragma unroll
      for (int c = 0; c < 4; ++c) {
        int i = i4 * 4 + c;
        if (i >= lo && i < e) {
          unsigned dd = (unsigned)dst[i];
          unsigned kk = dd >> BKT_BITS;
          pk[jj * 4 + c] = ((unsigned)src[i] << BKT_BITS) | (dd & (BKT - 1));
          b4 = (b4 & ~(0xFFu << (8 * c))) | (kk << (8 * c));
          atomicAdd(&cnt[kk], 1u);
        }
      }
    }
    bku[jj] = b4;
  }
  __syncthreads();

  if (tid < 64) {
    unsigned running = 0;
    for (int c = 0; c < NB; c += 64) {
      int k = c + tid;
      unsigned v = cnt[k];
      unsigned incl = v;
#pragma unroll
      for (int off = 1; off < 64; off <<= 1) {
        unsigned t = __shfl_up(incl, off);
        if (tid >= off) incl += t;
      }
      loff[k] = running + incl - v;
      running += __shfl(incl, 63);
    }
    if (tid == 0) loff[NB] = running;
  }
  __syncthreads();

  for (int k = tid; k < nbkt; k += SCT)
    if (cnt[k]) gseg[k] = atomicAdd(&gcur[k], cnt[k]);

#pragma unroll
  for (int jj = 0; jj < PERT / 4; ++jj) {
    unsigned b4 = bku[jj];
#pragma unroll
    for (int c = 0; c < 4; ++c) {
      unsigned k = (b4 >> (8 * c)) & 0xFFu;
      if (k != 0xFFu) {
        unsigned pos = loff[k] + atomicAdd(&cur[k], 1u);
        staged[pos] = pk[jj * 4 + c];
      }
    }
  }
  __syncthreads();

  int mv = (int)loff[NB];
  for (int t = tid; t < mv; t += SCT) {
    int a = 0, b = nbkt;
    while (b - a > 1) {
      int mid = (a + b) >> 1;
      if ((int)loff[mid] <= t) a = mid; else b = mid;
    }
    __builtin_nontemporal_store(staged[t],
                                packed + gseg[a] + (unsigned)(t - (int)loff[a]));
  }
}

// ---- 4. per-bucket slice sort (245 classes) + sliceoff + deg16 + xs ----
__global__ void __launch_bounds__(1024) k_classort(
    const unsigned* __restrict__ packed, const unsigned* __restrict__ gcur,
    const float* __restrict__ x, int n, unsigned* __restrict__ packed2,
    unsigned* __restrict__ sliceoff, unsigned short* __restrict__ deg16,
    float* __restrict__ xs) {
  __shared__ unsigned cnt_node[BKT];       // 8 KB
  __shared__ unsigned wcnt[NCLSP * NW];    // 15.5 KB
  __shared__ unsigned wcur[NCLSP * NW];    // 15.5 KB
  const int k = blockIdx.x;
  const int tid = threadIdx.x;
  const int w = tid >> 6;
  for (int t = tid; t < BKT; t += 1024) cnt_node[t] = 0;
  for (int t = tid; t < NCLSP * NW; t += 1024) wcnt[t] = 0;
  __syncthreads();
  unsigned lo = k ? gcur[k - 1] : 0u, hi = gcur[k];
  unsigned loA = (lo + 3u) & ~3u, hiA = hi & ~3u;
  if (loA > hi) loA = hi;
  if (hiA < loA) hiA = loA;

  for (unsigned i = lo + tid; i < loA; i += 1024) {
    unsigned p = packed[i];
    atomicAdd(&cnt_node[p & (BKT - 1)], 1u);
    atomicAdd(&wcnt[(p >> 22) * NW + w], 1u);
  }
  for (unsigned i = hiA + tid; i < hi; i += 1024) {
    unsigned p = packed[i];
    atomicAdd(&cnt_node[p & (BKT - 1)], 1u);
    atomicAdd(&wcnt[(p >> 22) * NW + w], 1u);
  }
  const u32x4* p4 = (const u32x4*)packed;
  for (unsigned q = (loA >> 2) + tid; q < (hiA >> 2); q += 1024) {
    u32x4 p = p4[q];
    atomicAdd(&cnt_node[p.x & (BKT - 1)], 1u);
    atomicAdd(&wcnt[(p.x >> 22) * NW + w], 1u);
    atomicAdd(&cnt_node[p.y & (BKT - 1)], 1u);
    atomicAdd(&wcnt[(p.y >> 22) * NW + w], 1u);
    atomicAdd(&cnt_node[p.z & (BKT - 1)], 1u);
    atomicAdd(&wcnt[(p.z >> 22) * NW + w], 1u);
    atomicAdd(&cnt_node[p.w & (BKT - 1)], 1u);
    atomicAdd(&wcnt[(p.w >> 22) * NW + w], 1u);
  }
  __syncthreads();

  if (tid < 64) {  // wave-0 scan; emit per-class starts
    unsigned running = 0;
    for (int c = 0; c < NCLSP * NW; c += 64) {
      int idx = c + tid;
      unsigned v = wcnt[idx];
      unsigned incl = v;
#pragma unroll
      for (int off = 1; off < 64; off <<= 1) {
        unsigned t = __shfl_up(incl, off);
        if (tid >= off) incl += t;
      }
      unsigned excl = running + incl - v;
      wcur[idx] = excl;
      if ((idx & (NW - 1)) == 0 && (idx >> 4) <= NCLS)
        sliceoff[k * (NCLS + 1) + (idx >> 4)] = excl;
      running += __shfl(incl, 63);
    }
  }
  __syncthreads();

  for (unsigned i = lo + tid; i < loA; i += 1024) {
    unsigned p = packed[i];
    packed2[lo + atomicAdd(&wcur[(p >> 22) * NW + w], 1u)] = p;
  }
  for (unsigned i = hiA + tid; i < hi; i += 1024) {
    unsigned p = packed[i];
    packed2[lo + atomicAdd(&wcur[(p >> 22) * NW + w], 1u)] = p;
  }
  for (unsigned q = (loA >> 2) + tid; q < (hiA >> 2); q += 1024) {
    u32x4 p = p4[q];
    packed2[lo + atomicAdd(&wcur[(p.x >> 22) * NW + w], 1u)] = p.x;
    packed2[lo + atomicAdd(&wcur[(p.y >> 22) * NW + w], 1u)] = p.y;
    packed2[lo + atomicAdd(&wcur[(p.z >> 22) * NW + w], 1u)] = p.z;
    packed2[lo + atomicAdd(&wcur[(p.w >> 22) * NW + w], 1u)] = p.w;
  }

  int g0 = k << BKT_BITS;
  for (int t = tid; t < BKT; t += 1024) {
    int g = g0 + t;
    if (g < n) {
      unsigned d = cnt_node[t];
      deg16[g] = (unsigned short)(d > 65535u ? 65535u : d);
      xs[g] = rsqrtf((float)(d + 1u)) * x[g];
    }
  }
}

// ---- 5. pass A: 12-bucket groups, double-buffered slice staging ----
__global__ void __launch_bounds__(1024) k_accA_grp(
    const unsigned* __restrict__ packed2, const unsigned* __restrict__ gcur,
    const unsigned* __restrict__ sliceoff, const float* __restrict__ xs, int n,
    int nbkt, float* __restrict__ pA) {
  __shared__ float acc[GA << BKT_BITS];  // 96 KB
  __shared__ float stg[2][BKT];          // 16 KB
  const int grp = blockIdx.x / RA, r = blockIdx.x % RA;
  const int tid = threadIdx.x;
  for (int t = tid; t < (GA << BKT_BITS); t += 1024) acc[t] = 0.0f;
  const int w = tid >> 6, lane = tid & 63;
  const int b = w % GA;                  // bucket-in-group for this wave
  const int wsub = w / GA;
  const unsigned nsub = (unsigned)((NW - 1 - b) / GA + 1);
  const int bk = grp * GA + b;
  const bool active = bk < nbkt;
  unsigned bs = 0;
  const unsigned* so = sliceoff;
  if (active) {
    bs = bk ? gcur[bk - 1] : 0u;
    so = sliceoff + (size_t)bk * (NCLS + 1);
  }
  const int s0 = r * NSA;
  const int s1 = min(s0 + NSA, NCLS);
  float r0, r1;
  {  // prologue: stage slice s0
    int base = s0 << BKT_BITS;
    r0 = (base + tid < n) ? xs[base + tid] : 0.0f;
    r1 = (base + tid + 1024 < n) ? xs[base + tid + 1024] : 0.0f;
    stg[0][tid] = r0;
    stg[0][tid + 1024] = r1;
  }
  __syncthreads();
  int cur = 0;
  for (int s = s0; s < s1; ++s) {
    if (s + 1 < s1) {  // issue next-slice loads early (T14)
      int base = (s + 1) << BKT_BITS;
      r0 = (base + tid < n) ? xs[base + tid] : 0.0f;
      r1 = (base + tid + 1024 < n) ? xs[base + tid + 1024] : 0.0f;
    }
    if (active) {
      unsigned slo = bs + so[s], shi = bs + so[s + 1];
      for (unsigned i = slo + (unsigned)(wsub * 64 + lane); i < shi;
           i += nsub * 64u) {
        unsigned ww = packed2[i];
        atomicAdd(&acc[(b << BKT_BITS) | (ww & (BKT - 1))],
                  stg[cur][(ww >> BKT_BITS) & (BKT - 1)]);
      }
    }
    __syncthreads();
    if (s + 1 < s1) {
      stg[cur ^ 1][tid] = r0;
      stg[cur ^ 1][tid + 1024] = r1;
    }
    __syncthreads();
    cur ^= 1;
  }
  const int gReal = min(GA, nbkt - grp * GA);
  size_t outbase = (size_t)r * ((size_t)nbkt << BKT_BITS) +
                   ((size_t)(grp * GA) << BKT_BITS);
  for (int t = tid; t < (gReal << BKT_BITS); t += 1024)
    __builtin_nontemporal_store(acc[t], pA + outbase + t);
}

// ---- 6. node epilogue A: merge RA partials + MLP 1->32->2 -> yd ----
__global__ void __launch_bounds__(256) k_nodeA(
    const float* __restrict__ pA, const unsigned short* __restrict__ deg16,
    const float* __restrict__ xs, const float* __restrict__ W1,
    const float* __restrict__ b1, const float* __restrict__ W2, int n, int nbkt,
    float2* __restrict__ yd) {
  __shared__ float sW1[32], sb1[32], sW2[64];
  if (threadIdx.x < 32) {
    sW1[threadIdx.x] = W1[threadIdx.x];
    sb1[threadIdx.x] = b1[threadIdx.x];
  } else if (threadIdx.x < 96) {
    sW2[threadIdx.x - 32] = W2[threadIdx.x - 32];
  }
  __syncthreads();
  int g = blockIdx.x * 256 + threadIdx.x;
  if (g >= n) return;
  size_t np = (size_t)nbkt << BKT_BITS;
  float a = 0.0f;
#pragma unroll
  for (int r = 0; r < RA; ++r) a += pA[(size_t)r * np + g];
  float di = rsqrtf((float)(deg16[g] + 1u));
  float sv = di * (a + xs[g]);  // self-loop: dinv^2*x = dinv*xs
  float y0 = 0.0f, y1 = 0.0f;
#pragma unroll
  for (int f = 0; f < 32; ++f) {
    float h = fmaxf(fmaf(sv, sW1[f], sb1[f]), 0.0f);
    y0 = fmaf(h, sW2[2 * f + 0], y0);
    y1 = fmaf(h, sW2[2 * f + 1], y1);
  }
  yd[g] = make_float2(di * y0, di * y1);
}

// ---- 7. pass B: 6-bucket groups, double-buffered float2 staging ----
__global__ void __launch_bounds__(1024) k_accB_grp(
    const unsigned* __restrict__ packed2, const unsigned* __restrict__ gcur,
    const unsigned* __restrict__ sliceoff, const float2* __restrict__ yd, int n,
    int nbkt, float2* __restrict__ pB) {
  __shared__ float a0[GB << BKT_BITS];  // 48 KB
  __shared__ float a1[GB << BKT_BITS];  // 48 KB
  __shared__ float2 stg[2][BKT];        // 32 KB  (total 128 KB)
  const int grp = blockIdx.x / RB, r = blockIdx.x % RB;
  const int tid = threadIdx.x;
  for (int t = tid; t < (GB << BKT_BITS); t += 1024) {
    a0[t] = 0.0f;
    a1[t] = 0.0f;
  }
  const int w = tid >> 6, lane = tid & 63;
  const int b = w % GB;
  const int wsub = w / GB;
  const unsigned nsub = (unsigned)((NW - 1 - b) / GB + 1);
  const int bk = grp * GB + b;
  const bool active = bk < nbkt;
  unsigned bs = 0;
  const unsigned* so = sliceoff;
  if (active) {
    bs = bk ? gcur[bk - 1] : 0u;
    so = sliceoff + (size_t)bk * (NCLS + 1);
  }
  const int s0 = r * NSB;
  const int s1 = min(s0 + NSB, NCLS);
  float2 r0, r1;
  {  // prologue: stage slice s0
    int base = s0 << BKT_BITS;
    r0 = (base + tid < n) ? yd[base + tid] : make_float2(0.0f, 0.0f);
    r1 = (base + tid + 1024 < n) ? yd[base + tid + 1024] : make_float2(0.0f, 0.0f);
    stg[0][tid] = r0;
    stg[0][tid + 1024] = r1;
  }
  __syncthreads();
  int cur = 0;
  for (int s = s0; s < s1; ++s) {
    if (s + 1 < s1) {
      int base = (s + 1) << BKT_BITS;
      r0 = (base + tid < n) ? yd[base + tid] : make_float2(0.0f, 0.0f);
      r1 = (base + tid + 1024 < n) ? yd[base + tid + 1024]
                                   : make_float2(0.0f, 0.0f);
    }
    if (active) {
      unsigned slo = bs + so[s], shi = bs + so[s + 1];
      for (unsigned i = slo + (unsigned)(wsub * 64 + lane); i < shi;
           i += nsub * 64u) {
        unsigned ww = packed2[i];
        unsigned d = (b << BKT_BITS) | (ww & (BKT - 1));
        float2 v = stg[cur][(ww >> BKT_BITS) & (BKT - 1)];
        atomicAdd(&a0[d], v.x);
        atomicAdd(&a1[d], v.y);
      }
    }
    __syncthreads();
    if (s + 1 < s1) {
      stg[cur ^ 1][tid] = r0;
      stg[cur ^ 1][tid + 1024] = r1;
    }
    __syncthreads();
    cur ^= 1;
  }
  const int gReal = min(GB, nbkt - grp * GB);
  size_t outbase = (size_t)r * ((size_t)nbkt << BKT_BITS) +
                   ((size_t)(grp * GB) << BKT_BITS);
  for (int t = tid; t < (gReal << BKT_BITS); t += 1024)
    pB[outbase + t] = make_float2(a0[t], a1[t]);
}

// ---- 8. node epilogue B: merge RB partials + log-softmax ----
__global__ void __launch_bounds__(256) k_nodeB(
    const float2* __restrict__ pB, const unsigned short* __restrict__ deg16,
    const float2* __restrict__ yd, const float* __restrict__ b2, int n, int nbkt,
    float2* __restrict__ out) {
  int g = blockIdx.x * 256 + threadIdx.x;
  if (g >= n) return;
  size_t np = (size_t)nbkt << BKT_BITS;
  float s0 = 0.0f, s1 = 0.0f;
#pragma unroll
  for (int r = 0; r < RB; ++r) {
    float2 v = pB[(size_t)r * np + g];
    s0 += v.x;
    s1 += v.y;
  }
  float di = rsqrtf((float)(deg16[g] + 1u));
  float2 yv = yd[g];
  float t0 = fmaf(di, s0 + yv.x, b2[0]);
  float t1 = fmaf(di, s1 + yv.y, b2[1]);
  float m = fmaxf(t0, t1);
  float l = m + logf(expf(t0 - m) + expf(t1 - m));
  out[g] = make_float2(t0 - l, t1 - l);
}

extern "C" void kernel_launch(void* const* d_in, const int* in_sizes, int n_in,
                              void* d_out, int out_size, void* d_ws, size_t ws_size,
                              hipStream_t stream) {
  const float* x = (const float*)d_in[0];
  const int* edge = (const int*)d_in[1];  // int64 inputs arrive as int32
  const float* W1 = (const float*)d_in[2];
  const float* b1 = (const float*)d_in[3];
  const float* W2 = (const float*)d_in[4];
  const float* b2 = (const float*)d_in[5];
  float2* out = (float2*)d_out;

  const int n = in_sizes[0];      // 500000
  const int e = in_sizes[1] / 2;  // 8000000
  const int* src = edge;
  const int* dst = edge + e;

  const int nbkt = (n + BKT - 1) >> BKT_BITS;         // 245
  const int hchunk = (((e + HB - 1) / HB) + 3) & ~3;  // mult of 4
  const int sgrid = (e + CHUNK - 1) / CHUNK;          // 977
  const int ngrid = (n + 255) / 256;                  // 1954
  const int gridA = ((nbkt + GA - 1) / GA) * RA;      // 21*12 = 252
  const int gridB = ((nbkt + GB - 1) / GB) * RB;      // 41*6  = 246

  // ---- workspace (~71.3 MB; proven to fit in round 9) ----
  char* ws = (char*)d_ws;
  size_t off = 0;
  unsigned* packed = (unsigned*)(ws + off);   off += (size_t)e * 4;  // 32 MB
  unsigned* packed2 = (unsigned*)(ws + off);  off += (size_t)e * 4;  // 32 MB
  unsigned* totals = (unsigned*)(ws + off);   off += NB * 4;
  unsigned* gcur = (unsigned*)(ws + off);     off += NB * 4;
  unsigned* sliceoff = (unsigned*)(ws + off); off += (size_t)nbkt * (NCLS + 1) * 4;
  unsigned short* deg16 = (unsigned short*)(ws + off); off += (size_t)n * 2;
  float* xs = (float*)(ws + off);             off += (size_t)n * 4;  // 2 MB
  float2* yd = (float2*)(ws + off);           off += (size_t)n * 8;  // 4 MB
  // partials overlay the (dead after classort) packed region:
  //   pA: RA * (nbkt<<11) * 4B = 24.08 MB;  pB: RB * (nbkt<<11) * 8B = 24.08 MB
  float* pA = (float*)packed;
  float2* pB = (float2*)packed;

  hipMemsetAsync(totals, 0, NB * sizeof(unsigned), stream);
  k_hist<<<HB, HT, 0, stream>>>(dst, e, hchunk, nbkt, totals);
  k_basescan<<<1, 64, 0, stream>>>(totals, nbkt, gcur);
  k_scatter<<<sgrid, SCT, 0, stream>>>(src, dst, e, nbkt, gcur, packed);
  // after k_scatter: gcur[k] == end of bucket k
  k_classort<<<nbkt, 1024, 0, stream>>>(packed, gcur, x, n, packed2, sliceoff,
                                        deg16, xs);
  k_accA_grp<<<gridA, 1024, 0, stream>>>(packed2, gcur, sliceoff, xs, n, nbkt,
                                         pA);
  k_nodeA<<<ngrid, 256, 0, stream>>>(pA, deg16, xs, W1, b1, W2, n, nbkt, yd);
  k_accB_grp<<<gridB, 1024, 0, stream>>>(packed2, gcur, sliceoff, yd, n, nbkt,
                                         pB);
  k_nodeB<<<ngrid, 256, 0, stream>>>(pB, deg16, yd, b2, n, nbkt, out);
}